// Round 3
// baseline (569.224 us; speedup 1.0000x reference)
//
#include <hip/hip_runtime.h>
#include <cstdint>
#include <cstddef>

// LSTM cell: g = [X|Hprev] @ [Wih|Whh]^T + b -> gates -> (h_new, c_new)
// Round 6: pass 1 (fp32->fp16 into d_ws) unchanged.
// Pass 2 v5: identical pipeline to v4 (256x256 tile, 8 waves, ring-4 LDS,
// register frag pipeline, 1 barrier + counted vmcnt per tile) with ONE change:
//   block mapping is now hblk-FAST within each XCD chunk:
//     hblk = (bx % 16) * 64, m0 = (bx / 16) * 256
//   so the 32 co-resident blocks per XCD share 2 A-panels (2MB) + a 288KB/tile
//   sliding K-window -> A-panel HBM fetch drops from 8x64MB to 1x64MB total.
//   (Round-2 counters: FETCH_SIZE 573MB vs 144MB ideal = HBM-refetch bound;
//    573MB @ 2.36TB/s = 243us of the 305us dispatch.)
// Verified-unchanged: XOR chunk swizzle, gate-interleaved B, register epilogue.

typedef _Float16 half8 __attribute__((ext_vector_type(8)));
typedef float f32x4 __attribute__((ext_vector_type(4)));

__device__ __forceinline__ float sigmoidf_(float x) { return 1.0f / (1.0f + __expf(-x)); }
__device__ __forceinline__ float tanh_fast(float x) { return 2.0f / (1.0f + __expf(-2.0f * x)) - 1.0f; }

__device__ __forceinline__ void gld16(const void* g, void* lds) {
    // 16B/lane async global->LDS; lds base must be wave-uniform (dest = base + lane*16)
    __builtin_amdgcn_global_load_lds((const __attribute__((address_space(1))) uint32_t*)g,
                                     (__attribute__((address_space(3))) uint32_t*)lds, 16, 0, 0);
}

// ---------------- pass 1: fp32 -> fp16 ----------------
__global__ __launch_bounds__(256)
void convert_to_f16(const float* __restrict__ X, const float* __restrict__ H,
                    const float* __restrict__ Wih, const float* __restrict__ Whh,
                    _Float16* __restrict__ ws, long nX, long nW)
{
    long e = ((long)blockIdx.x * 256 + threadIdx.x) * 8;
    long total = 2 * nX + 2 * nW;
    if (e >= total) return;
    const float* src; long off;
    if (e < nX)              { src = X;   off = e; }
    else if (e < 2 * nX)     { src = H;   off = e - nX; }
    else if (e < 2 * nX + nW){ src = Wih; off = e - 2 * nX; }
    else                     { src = Whh; off = e - 2 * nX - nW; }
    float4 a = *(const float4*)(src + off);
    float4 b = *(const float4*)(src + off + 4);
    half8 h;
    h[0]=(_Float16)a.x; h[1]=(_Float16)a.y; h[2]=(_Float16)a.z; h[3]=(_Float16)a.w;
    h[4]=(_Float16)b.x; h[5]=(_Float16)b.y; h[6]=(_Float16)b.z; h[7]=(_Float16)b.w;
    *(half8*)(ws + e) = h;
}

// ---------------- pass 2: 256x256 8-wave register-pipelined MFMA GEMM + fused gates ----------------
__global__ __launch_bounds__(512, 2)
void lstm_mfma_v5(const _Float16* __restrict__ ws,   // Xh | Hh | Wih_h | Whh_h
                  const float* __restrict__ Cprev,
                  const float* __restrict__ bih, const float* __restrict__ bhh,
                  float* __restrict__ Out, int Btot, int mblocks)
{
    // A ring: 4 bufs x 16KB at [0, 64K); B ring: 4 bufs x 16KB at [64K, 128K)
    __shared__ alignas(16) char smem[131072];

    const long nX = (long)Btot * 1024;
    const long nW = 4096L * 1024;
    const _Float16* Xh = ws;
    const _Float16* Hh = ws + nX;
    const _Float16* Wi = ws + 2 * nX;
    const _Float16* Wh = ws + 2 * nX + nW;

    const int tid = threadIdx.x;
    const int w = tid >> 6, l = tid & 63;
    const int lr = l & 15, q = l >> 4;
    const int wm = w >> 2, wn = w & 3;                // wave grid: 2 (M) x 4 (N)

    // XCD-aware chunked swizzle (bijective when nwg % 8 == 0; nwg = 1024 here)
    const int nwg = gridDim.x;
    int bx = blockIdx.x;
    if ((nwg & 7) == 0) bx = (bx & 7) * (nwg >> 3) + (bx >> 3);
    // hblk-FAST mapping: co-resident blocks on an XCD share A-panels (L2 reuse)
    const int hblk = (bx & 15) * 64;
    const int m0   = (bx >> 4) * 256;

    // ---- staging precompute: issue j (0,1) covers LDS bytes [j*8192 + w*1024 + l*16] ----
    // tile rows are 64B (BK=32 halves); LDS chunk cl holds global k-chunk cl ^ ((r>>1)&3)
    uint32_t gA[2], gB[2], ub[2];
    #pragma unroll
    for (int j = 0; j < 2; ++j) {
        uint32_t u = (uint32_t)(j * 8192 + w * 1024);
        ub[j] = u;
        uint32_t off = u + (uint32_t)l * 16u;
        uint32_t r  = off >> 6;                        // tile row 0..255
        uint32_t c  = ((off >> 4) & 3u) ^ ((r >> 1) & 3u);
        gA[j] = (uint32_t)(m0 + (int)r) * 1024u + c * 8u;
        uint32_t gate = (r >> 4) & 3u;                 // gate-interleaved B rows
        uint32_t hsub = (r >> 6) * 16u + (r & 15u);
        gB[j] = (gate * 1024u + (uint32_t)hblk + hsub) * 1024u + c * 8u;
    }

    // ---- fragment-read byte offsets (swizzled chunk) ----
    const int sw = (lr >> 1) & 3;
    const int ck = (q ^ sw) * 16;
    const uint32_t aB0 = (uint32_t)((wm * 128 + lr) * 64 + ck);  // + mt*1024
    const uint32_t bB0 = (uint32_t)((wn * 64  + lr) * 64 + ck);  // + nt*1024

    f32x4 acc[8][4];
    #pragma unroll
    for (int i = 0; i < 8; ++i)
        #pragma unroll
        for (int j = 0; j < 4; ++j)
            acc[i][j] = (f32x4){0.f, 0.f, 0.f, 0.f};

    auto stage = [&](int ts, int sb) {
        const _Float16* Ap = (ts < 32) ? Xh : Hh;
        const _Float16* Bp = (ts < 32) ? Wi : Wh;
        const uint32_t k0 = (uint32_t)(ts & 31) * 32u;
        char* bA = smem + sb * 16384;
        char* bB = smem + 65536 + sb * 16384;
        gld16(Ap + gA[0] + k0, bA + ub[0]);
        gld16(Ap + gA[1] + k0, bA + ub[1]);
        gld16(Bp + gB[0] + k0, bB + ub[0]);
        gld16(Bp + gB[1] + k0, bB + ub[1]);
    };

    // rotating fragment register sets (static names -> no scratch, rule #20)
    half8 afA[4], bfA[4], agA[4];
    half8 afB[4], bfB[4], agB[4];

    // ---- prologue: fill depth-3 ring; publish buffers 0,1; preload tile-0 frags ----
    stage(0, 0); stage(1, 1); stage(2, 2);
    asm volatile("s_waitcnt vmcnt(4)" ::: "memory");   // stages 0,1 landed
    __builtin_amdgcn_s_barrier();                      // buffers 0,1 published
    #pragma unroll
    for (int i = 0; i < 4; ++i) bfA[i] = *(const half8*)(smem + 65536 + bB0 + i * 1024);
    #pragma unroll
    for (int i = 0; i < 4; ++i) afA[i] = *(const half8*)(smem + aB0 + i * 1024);
    #pragma unroll
    for (int i = 0; i < 4; ++i) agA[i] = *(const half8*)(smem + aB0 + (i + 4) * 1024);

    // One tile: consume CUR set, prefetch NXT set (tile t+1) between MFMA clusters.
    // Tail (t=63): NXT reads target dummy tile 63 data (never consumed) - uniform code.
#define TILE_HALF(T, CAF, CBF, CAG, NAF, NBF, NAG)                                   \
    {                                                                                \
        const int t_ = (T);                                                          \
        int ts_ = t_ + 3; if (ts_ > 63) ts_ = 63;                                    \
        stage(ts_, (t_ + 3) & 3);                                                    \
        const char* sAn = smem + ((t_ + 1) & 3) * 16384;                             \
        const char* sBn = smem + 65536 + ((t_ + 1) & 3) * 16384;                     \
        _Pragma("unroll")                                                            \
        for (int i = 0; i < 4; ++i) NBF[i] = *(const half8*)(sBn + bB0 + i * 1024);  \
        __builtin_amdgcn_s_setprio(1);                                               \
        _Pragma("unroll")                                                            \
        for (int mt = 0; mt < 4; ++mt)                                               \
            _Pragma("unroll")                                                        \
            for (int nt = 0; nt < 4; ++nt)                                           \
                acc[mt][nt] = __builtin_amdgcn_mfma_f32_16x16x32_f16(CAF[mt], CBF[nt], acc[mt][nt], 0, 0, 0); \
        __builtin_amdgcn_s_setprio(0);                                               \
        _Pragma("unroll")                                                            \
        for (int i = 0; i < 4; ++i) NAF[i] = *(const half8*)(sAn + aB0 + i * 1024);  \
        __builtin_amdgcn_s_setprio(1);                                               \
        _Pragma("unroll")                                                            \
        for (int mt = 0; mt < 4; ++mt)                                               \
            _Pragma("unroll")                                                        \
            for (int nt = 0; nt < 4; ++nt)                                           \
                acc[mt + 4][nt] = __builtin_amdgcn_mfma_f32_16x16x32_f16(CAG[mt], CBF[nt], acc[mt + 4][nt], 0, 0, 0); \
        __builtin_amdgcn_s_setprio(0);                                               \
        _Pragma("unroll")                                                            \
        for (int i = 0; i < 4; ++i) NAG[i] = *(const half8*)(sAn + aB0 + (i + 4) * 1024); \
        asm volatile("s_waitcnt vmcnt(4)" ::: "memory");                             \
        __builtin_amdgcn_s_barrier();                                                \
    }

    #pragma unroll 1
    for (int p = 0; p < 32; ++p) {
        TILE_HALF(2 * p,     afA, bfA, agA, afB, bfB, agB)
        TILE_HALF(2 * p + 1, afB, bfB, agB, afA, bfA, agA)
    }
#undef TILE_HALF
    asm volatile("s_waitcnt vmcnt(0)" ::: "memory");   // drain clamped tail stages

    // ---- epilogue: register-only. acc[mt][g][r]: m = m0+wm*128+mt*16+q*4+r,
    //      gate g, h = hblk + wn*16 + lr  (all 4 gates in-thread) ----
    const int h = hblk + wn * 16 + lr;
    float bs[4];
    #pragma unroll
    for (int g = 0; g < 4; ++g) bs[g] = bih[g * 1024 + h] + bhh[g * 1024 + h];
    const long c_off = (long)Btot * 1024;
    const int mbase = m0 + wm * 128 + q * 4;

    #pragma unroll
    for (int mt = 0; mt < 8; ++mt) {
        #pragma unroll
        for (int r = 0; r < 4; ++r) {
            const int m = mbase + mt * 16 + r;
            const long idx = (long)m * 1024 + h;
            float gi = acc[mt][0][r] + bs[0];
            float gf = acc[mt][1][r] + bs[1];
            float gc = acc[mt][2][r] + bs[2];
            float go = acc[mt][3][r] + bs[3];
            float ig = sigmoidf_(gi), fg = sigmoidf_(gf);
            float cd = tanh_fast(gc), og = sigmoidf_(go);
            float c_new = Cprev[idx] * fg + ig * cd;
            Out[idx]         = tanh_fast(c_new) * og;
            Out[c_off + idx] = c_new;
        }
    }
}

// ---------------- fallback (round-2 kernel): used only if ws too small ----------------
__global__ __launch_bounds__(256, 2)
void lstm_mfma_f16_fb(const float* __restrict__ X, const float* __restrict__ Hprev,
                      const float* __restrict__ Cprev,
                      const float* __restrict__ Wih, const float* __restrict__ Whh,
                      const float* __restrict__ bih, const float* __restrict__ bhh,
                      float* __restrict__ Out, int Btot, int mblocks)
{
    __shared__ alignas(16) _Float16 As[128][40];
    __shared__ alignas(16) _Float16 Bs[256][40];
    const int tid = threadIdx.x;
    const int w = tid >> 6, lane = tid & 63, lr = lane & 15, q = lane >> 4;
    const int bx = blockIdx.x, mblk = bx % mblocks, nblk = bx / mblocks;
    const int m0 = mblk * 128, hblk = nblk * 64;
    const int sr = tid >> 1, sc = tid & 1;
    f32x4 acc[8][4];
    #pragma unroll
    for (int mt = 0; mt < 8; ++mt)
        #pragma unroll
        for (int g = 0; g < 4; ++g) acc[mt][g] = (f32x4){0.f,0.f,0.f,0.f};
    float4 pa[4], pb0[4], pb1[4];
    const int rb1 = sr + 128;
    const size_t wrow0 = (size_t)((sr >> 6) * 1024 + hblk + (sr & 63)) * 1024;
    const size_t wrow1 = (size_t)((rb1 >> 6) * 1024 + hblk + (rb1 & 63)) * 1024;
    const size_t arow  = (size_t)(m0 + sr) * 1024;
    auto stage_load = [&](int tile) {
        const int phase = tile >> 5;
        const int k0 = (tile & 31) * 32 + sc * 16;
        const float* Ap = phase ? Hprev : X;
        const float* Wp = phase ? Whh : Wih;
        const float4* ap = (const float4*)(Ap + arow + k0);
        const float4* b0 = (const float4*)(Wp + wrow0 + k0);
        const float4* b1 = (const float4*)(Wp + wrow1 + k0);
        #pragma unroll
        for (int i = 0; i < 4; ++i) { pa[i] = ap[i]; pb0[i] = b0[i]; pb1[i] = b1[i]; }
    };
    auto pack8 = [](float4 a, float4 b) {
        half8 h;
        h[0]=(_Float16)a.x; h[1]=(_Float16)a.y; h[2]=(_Float16)a.z; h[3]=(_Float16)a.w;
        h[4]=(_Float16)b.x; h[5]=(_Float16)b.y; h[6]=(_Float16)b.z; h[7]=(_Float16)b.w;
        return h;
    };
    stage_load(0);
    for (int tile = 0; tile < 64; ++tile) {
        __syncthreads();
        *(half8*)&As[sr][sc*16]        = pack8(pa[0], pa[1]);
        *(half8*)&As[sr][sc*16+8]      = pack8(pa[2], pa[3]);
        *(half8*)&Bs[sr][sc*16]        = pack8(pb0[0], pb0[1]);
        *(half8*)&Bs[sr][sc*16+8]      = pack8(pb0[2], pb0[3]);
        *(half8*)&Bs[sr+128][sc*16]    = pack8(pb1[0], pb1[1]);
        *(half8*)&Bs[sr+128][sc*16+8]  = pack8(pb1[2], pb1[3]);
        __syncthreads();
        if (tile + 1 < 64) stage_load(tile + 1);
        half8 bf[4];
        #pragma unroll
        for (int g = 0; g < 4; ++g) bf[g] = *(const half8*)&Bs[g*64 + w*16 + lr][q*8];
        #pragma unroll
        for (int mt = 0; mt < 8; ++mt) {
            half8 a = *(const half8*)&As[mt*16 + lr][q*8];
            #pragma unroll
            for (int g = 0; g < 4; ++g)
                acc[mt][g] = __builtin_amdgcn_mfma_f32_16x16x32_f16(a, bf[g], acc[mt][g], 0, 0, 0);
        }
    }
    const int h = hblk + w * 16 + lr;
    float bs0 = bih[h] + bhh[h];
    float bs1 = bih[1024+h] + bhh[1024+h];
    float bs2 = bih[2048+h] + bhh[2048+h];
    float bs3 = bih[3072+h] + bhh[3072+h];
    const size_t c_off = (size_t)Btot * 1024;
    #pragma unroll
    for (int mt = 0; mt < 8; ++mt)
        #pragma unroll
        for (int r = 0; r < 4; ++r) {
            const int m = m0 + mt*16 + q*4 + r;
            const size_t idx = (size_t)m * 1024 + h;
            float gi = acc[mt][0][r]+bs0, gf = acc[mt][1][r]+bs1;
            float gc = acc[mt][2][r]+bs2, go = acc[mt][3][r]+bs3;
            float ig = sigmoidf_(gi), fg = sigmoidf_(gf);
            float cd = tanh_fast(gc), og = sigmoidf_(go);
            float c_new = Cprev[idx]*fg + ig*cd;
            Out[idx] = tanh_fast(c_new)*og;
            Out[c_off+idx] = c_new;
        }
}

extern "C" void kernel_launch(void* const* d_in, const int* in_sizes, int n_in,
                              void* d_out, int out_size, void* d_ws, size_t ws_size,
                              hipStream_t stream) {
    const float* X     = (const float*)d_in[0];
    const float* Hprev = (const float*)d_in[1];
    const float* Cprev = (const float*)d_in[2];
    const float* Wih   = (const float*)d_in[3];
    const float* Whh   = (const float*)d_in[4];
    const float* bih   = (const float*)d_in[5];
    const float* bhh   = (const float*)d_in[6];
    float* Out = (float*)d_out;

    const int Btot = in_sizes[0] / 1024;
    const long nX = (long)Btot * 1024, nW = 4096L * 1024;
    const size_t need = (size_t)(2 * nX + 2 * nW) * sizeof(_Float16);

    if (ws_size >= need && (Btot % 256) == 0) {
        _Float16* ws = (_Float16*)d_ws;
        const long total = 2 * nX + 2 * nW;
        const int cblocks = (int)((total / 8 + 255) / 256);
        hipLaunchKernelGGL(convert_to_f16, dim3(cblocks), dim3(256), 0, stream,
                           X, Hprev, Wih, Whh, ws, nX, nW);
        const int mblocks = Btot / 256;               // 64
        const int nblocks = 1024 / 64;                // 16
        hipLaunchKernelGGL(lstm_mfma_v5, dim3(mblocks * nblocks), dim3(512), 0, stream,
                           ws, Cprev, bih, bhh, Out, Btot, mblocks);
    } else {
        const int mblocks = Btot / 128;
        hipLaunchKernelGGL(lstm_mfma_f16_fb, dim3(mblocks * 16), dim3(256), 0, stream,
                           X, Hprev, Cprev, Wih, Whh, bih, bhh, Out, Btot, mblocks);
    }
}

// Round 4
// 553.212 us; speedup vs baseline: 1.0289x; 1.0289x over previous
//
#include <hip/hip_runtime.h>
#include <cstdint>
#include <cstddef>

// LSTM cell: g = [X|Hprev] @ [Wih|Whh]^T + b -> gates -> (h_new, c_new)
// Round 7: pass 1 (fp32->fp16 into d_ws) unchanged; hblk-fast XCD mapping kept
// (r3: FETCH 573->328MB). Pass 2 v6: m201-style phase schedule at BK=32:
//   per K-tile, 2 phases of {frag ds_reads (JIT) + 2 gld16 stage -> s_barrier ->
//   lgkmcnt(0) -> setprio(1) -> 16 MFMA burst -> setprio(0) -> s_barrier};
//   vmcnt(8) once per tile (ring-4: only tile t+1 must be resident).
//   Mechanism (m201/m196): waves issue the MFMA burst fast, cross the barrier
//   while the matrix pipe drains, and issue next phase's ds_reads under the
//   drain -> LDS pipe and matrix pipe overlap. r2/r3 counters showed the old
//   1-barrier reg-pipeline serialized them (2860 cyc/tile = 1320 MFMA + 1150 LDS).
//   Loop unrolled x4 so LDS slot offsets fold into ds_read immediates.
// Verified-unchanged: XOR chunk swizzle (conflicts=0), gate-interleaved B,
// register-only epilogue.

typedef _Float16 half8 __attribute__((ext_vector_type(8)));
typedef float f32x4 __attribute__((ext_vector_type(4)));

__device__ __forceinline__ float sigmoidf_(float x) { return 1.0f / (1.0f + __expf(-x)); }
__device__ __forceinline__ float tanh_fast(float x) { return 2.0f / (1.0f + __expf(-2.0f * x)) - 1.0f; }

__device__ __forceinline__ void gld16(const void* g, void* lds) {
    // 16B/lane async global->LDS; lds base must be wave-uniform (dest = base + lane*16)
    __builtin_amdgcn_global_load_lds((const __attribute__((address_space(1))) uint32_t*)g,
                                     (__attribute__((address_space(3))) uint32_t*)lds, 16, 0, 0);
}

// ---------------- pass 1: fp32 -> fp16 ----------------
__global__ __launch_bounds__(256)
void convert_to_f16(const float* __restrict__ X, const float* __restrict__ H,
                    const float* __restrict__ Wih, const float* __restrict__ Whh,
                    _Float16* __restrict__ ws, long nX, long nW)
{
    long e = ((long)blockIdx.x * 256 + threadIdx.x) * 8;
    long total = 2 * nX + 2 * nW;
    if (e >= total) return;
    const float* src; long off;
    if (e < nX)              { src = X;   off = e; }
    else if (e < 2 * nX)     { src = H;   off = e - nX; }
    else if (e < 2 * nX + nW){ src = Wih; off = e - 2 * nX; }
    else                     { src = Whh; off = e - 2 * nX - nW; }
    float4 a = *(const float4*)(src + off);
    float4 b = *(const float4*)(src + off + 4);
    half8 h;
    h[0]=(_Float16)a.x; h[1]=(_Float16)a.y; h[2]=(_Float16)a.z; h[3]=(_Float16)a.w;
    h[4]=(_Float16)b.x; h[5]=(_Float16)b.y; h[6]=(_Float16)b.z; h[7]=(_Float16)b.w;
    *(half8*)(ws + e) = h;
}

// ---------------- pass 2: 256x256 8-wave phase-scheduled MFMA GEMM + fused gates ----------------
__global__ __launch_bounds__(512, 2)
void lstm_mfma_v6(const _Float16* __restrict__ ws,   // Xh | Hh | Wih_h | Whh_h
                  const float* __restrict__ Cprev,
                  const float* __restrict__ bih, const float* __restrict__ bhh,
                  float* __restrict__ Out, int Btot, int mblocks)
{
    // A ring: 4 bufs x 16KB at [0, 64K); B ring: 4 bufs x 16KB at [64K, 128K)
    __shared__ alignas(16) char smem[131072];

    const long nX = (long)Btot * 1024;
    const long nW = 4096L * 1024;
    const _Float16* Xh = ws;
    const _Float16* Hh = ws + nX;
    const _Float16* Wi = ws + 2 * nX;
    const _Float16* Wh = ws + 2 * nX + nW;

    const int tid = threadIdx.x;
    const int w = tid >> 6, l = tid & 63;
    const int lr = l & 15, q = l >> 4;
    const int wm = w >> 2, wn = w & 3;                // wave grid: 2 (M) x 4 (N)

    // XCD-aware chunked swizzle (bijective when nwg % 8 == 0; nwg = 1024 here)
    const int nwg = gridDim.x;
    int bx = blockIdx.x;
    if ((nwg & 7) == 0) bx = (bx & 7) * (nwg >> 3) + (bx >> 3);
    // hblk-FAST mapping: co-resident blocks on an XCD share A-panels (L2 reuse)
    const int hblk = (bx & 15) * 64;
    const int m0   = (bx >> 4) * 256;

    // ---- staging precompute: issue j (0,1) covers LDS bytes [j*8192 + w*1024 + l*16] ----
    // tile rows are 64B (BK=32 halves); LDS chunk cl holds global k-chunk cl ^ ((r>>1)&3)
    uint32_t gA[2], gB[2], ub[2];
    #pragma unroll
    for (int j = 0; j < 2; ++j) {
        uint32_t u = (uint32_t)(j * 8192 + w * 1024);
        ub[j] = u;
        uint32_t off = u + (uint32_t)l * 16u;
        uint32_t r  = off >> 6;                        // tile row 0..255
        uint32_t c  = ((off >> 4) & 3u) ^ ((r >> 1) & 3u);
        gA[j] = (uint32_t)(m0 + (int)r) * 1024u + c * 8u;
        uint32_t gate = (r >> 4) & 3u;                 // gate-interleaved B rows
        uint32_t hsub = (r >> 6) * 16u + (r & 15u);
        gB[j] = (gate * 1024u + (uint32_t)hblk + hsub) * 1024u + c * 8u;
    }

    // ---- fragment-read base addresses (swizzled chunk); slot offsets fold into imm ----
    const int sw = (lr >> 1) & 3;
    const int ck = (q ^ sw) * 16;
    const char* adA = smem + (uint32_t)((wm * 128 + lr) * 64 + ck);          // + slot*16384 + mt*1024
    const char* adB = smem + 65536u + (uint32_t)((wn * 64 + lr) * 64 + ck);  // + slot*16384 + nt*1024

    f32x4 acc[8][4];
    #pragma unroll
    for (int i = 0; i < 8; ++i)
        #pragma unroll
        for (int j = 0; j < 4; ++j)
            acc[i][j] = (f32x4){0.f, 0.f, 0.f, 0.f};

    auto stageA = [&](int ts, int sb) {
        const _Float16* Ap = (ts < 32) ? Xh : Hh;
        const uint32_t k0 = (uint32_t)(ts & 31) * 32u;
        char* bA = smem + sb * 16384;
        gld16(Ap + gA[0] + k0, bA + ub[0]);
        gld16(Ap + gA[1] + k0, bA + ub[1]);
    };
    auto stageB = [&](int ts, int sb) {
        const _Float16* Bp = (ts < 32) ? Wi : Wh;
        const uint32_t k0 = (uint32_t)(ts & 31) * 32u;
        char* bB = smem + 65536 + sb * 16384;
        gld16(Bp + gB[0] + k0, bB + ub[0]);
        gld16(Bp + gB[1] + k0, bB + ub[1]);
    };

    // ---- prologue: fill depth-3 ring; confirm tile 0 resident ----
    stageA(0, 0); stageB(0, 0);
    stageA(1, 1); stageB(1, 1);
    stageA(2, 2); stageB(2, 2);
    asm volatile("s_waitcnt vmcnt(8)" ::: "memory");   // tile 0 (oldest 4) landed
    __builtin_amdgcn_s_barrier();

    // One K-tile, two phases. JIT frag reads; stage split across phases; 4 barriers.
    // WAR safety: stage(t+3) targets slot (t-1)&3, whose reads all retired before
    // the end-of-(t-1) barrier, which every wave crossed before any stage here.
#define TILE(T, SLOT)                                                                \
    {                                                                                \
        int ts_ = (T) + 3; if (ts_ > 63) ts_ = 63;                                   \
        const int sb_ = ((T) + 3) & 3;                                               \
        half8 af[4], bf[4], ag[4];                                                   \
        _Pragma("unroll")                                                            \
        for (int i = 0; i < 4; ++i) bf[i] = *(const half8*)(adB + (SLOT) * 16384 + i * 1024); \
        _Pragma("unroll")                                                            \
        for (int i = 0; i < 4; ++i) af[i] = *(const half8*)(adA + (SLOT) * 16384 + i * 1024); \
        stageA(ts_, sb_);                                                            \
        __builtin_amdgcn_s_barrier();                                                \
        asm volatile("s_waitcnt lgkmcnt(0)" ::: "memory");                           \
        __builtin_amdgcn_s_setprio(1);                                               \
        _Pragma("unroll")                                                            \
        for (int mt = 0; mt < 4; ++mt)                                               \
            _Pragma("unroll")                                                        \
            for (int nt = 0; nt < 4; ++nt)                                           \
                acc[mt][nt] = __builtin_amdgcn_mfma_f32_16x16x32_f16(af[mt], bf[nt], acc[mt][nt], 0, 0, 0); \
        __builtin_amdgcn_s_setprio(0);                                               \
        __builtin_amdgcn_s_barrier();                                                \
        _Pragma("unroll")                                                            \
        for (int i = 0; i < 4; ++i) ag[i] = *(const half8*)(adA + (SLOT) * 16384 + (i + 4) * 1024); \
        stageB(ts_, sb_);                                                            \
        __builtin_amdgcn_s_barrier();                                                \
        asm volatile("s_waitcnt lgkmcnt(0)" ::: "memory");                           \
        __builtin_amdgcn_s_setprio(1);                                               \
        _Pragma("unroll")                                                            \
        for (int mt = 0; mt < 4; ++mt)                                               \
            _Pragma("unroll")                                                        \
            for (int nt = 0; nt < 4; ++nt)                                           \
                acc[mt + 4][nt] = __builtin_amdgcn_mfma_f32_16x16x32_f16(ag[mt], bf[nt], acc[mt + 4][nt], 0, 0, 0); \
        __builtin_amdgcn_s_setprio(0);                                               \
        asm volatile("s_waitcnt vmcnt(8)" ::: "memory");                             \
        __builtin_amdgcn_s_barrier();                                                \
    }

    #pragma unroll 1
    for (int p = 0; p < 16; ++p) {
        TILE(4 * p + 0, 0)
        TILE(4 * p + 1, 1)
        TILE(4 * p + 2, 2)
        TILE(4 * p + 3, 3)
    }
#undef TILE
    asm volatile("s_waitcnt vmcnt(0)" ::: "memory");   // drain clamped tail stages

    // ---- epilogue: register-only. acc[mt][g][r]: m = m0+wm*128+mt*16+q*4+r,
    //      gate g, h = hblk + wn*16 + lr  (all 4 gates in-thread) ----
    const int h = hblk + wn * 16 + lr;
    float bs[4];
    #pragma unroll
    for (int g = 0; g < 4; ++g) bs[g] = bih[g * 1024 + h] + bhh[g * 1024 + h];
    const long c_off = (long)Btot * 1024;
    const int mbase = m0 + wm * 128 + q * 4;

    #pragma unroll
    for (int mt = 0; mt < 8; ++mt) {
        #pragma unroll
        for (int r = 0; r < 4; ++r) {
            const int m = mbase + mt * 16 + r;
            const long idx = (long)m * 1024 + h;
            float gi = acc[mt][0][r] + bs[0];
            float gf = acc[mt][1][r] + bs[1];
            float gc = acc[mt][2][r] + bs[2];
            float go = acc[mt][3][r] + bs[3];
            float ig = sigmoidf_(gi), fg = sigmoidf_(gf);
            float cd = tanh_fast(gc), og = sigmoidf_(go);
            float c_new = Cprev[idx] * fg + ig * cd;
            Out[idx]         = tanh_fast(c_new) * og;
            Out[c_off + idx] = c_new;
        }
    }
}

// ---------------- fallback (round-2 kernel): used only if ws too small ----------------
__global__ __launch_bounds__(256, 2)
void lstm_mfma_f16_fb(const float* __restrict__ X, const float* __restrict__ Hprev,
                      const float* __restrict__ Cprev,
                      const float* __restrict__ Wih, const float* __restrict__ Whh,
                      const float* __restrict__ bih, const float* __restrict__ bhh,
                      float* __restrict__ Out, int Btot, int mblocks)
{
    __shared__ alignas(16) _Float16 As[128][40];
    __shared__ alignas(16) _Float16 Bs[256][40];
    const int tid = threadIdx.x;
    const int w = tid >> 6, lane = tid & 63, lr = lane & 15, q = lane >> 4;
    const int bx = blockIdx.x, mblk = bx % mblocks, nblk = bx / mblocks;
    const int m0 = mblk * 128, hblk = nblk * 64;
    const int sr = tid >> 1, sc = tid & 1;
    f32x4 acc[8][4];
    #pragma unroll
    for (int mt = 0; mt < 8; ++mt)
        #pragma unroll
        for (int g = 0; g < 4; ++g) acc[mt][g] = (f32x4){0.f,0.f,0.f,0.f};
    float4 pa[4], pb0[4], pb1[4];
    const int rb1 = sr + 128;
    const size_t wrow0 = (size_t)((sr >> 6) * 1024 + hblk + (sr & 63)) * 1024;
    const size_t wrow1 = (size_t)((rb1 >> 6) * 1024 + hblk + (rb1 & 63)) * 1024;
    const size_t arow  = (size_t)(m0 + sr) * 1024;
    auto stage_load = [&](int tile) {
        const int phase = tile >> 5;
        const int k0 = (tile & 31) * 32 + sc * 16;
        const float* Ap = phase ? Hprev : X;
        const float* Wp = phase ? Whh : Wih;
        const float4* ap = (const float4*)(Ap + arow + k0);
        const float4* b0 = (const float4*)(Wp + wrow0 + k0);
        const float4* b1 = (const float4*)(Wp + wrow1 + k0);
        #pragma unroll
        for (int i = 0; i < 4; ++i) { pa[i] = ap[i]; pb0[i] = b0[i]; pb1[i] = b1[i]; }
    };
    auto pack8 = [](float4 a, float4 b) {
        half8 h;
        h[0]=(_Float16)a.x; h[1]=(_Float16)a.y; h[2]=(_Float16)a.z; h[3]=(_Float16)a.w;
        h[4]=(_Float16)b.x; h[5]=(_Float16)b.y; h[6]=(_Float16)b.z; h[7]=(_Float16)b.w;
        return h;
    };
    stage_load(0);
    for (int tile = 0; tile < 64; ++tile) {
        __syncthreads();
        *(half8*)&As[sr][sc*16]        = pack8(pa[0], pa[1]);
        *(half8*)&As[sr][sc*16+8]      = pack8(pa[2], pa[3]);
        *(half8*)&Bs[sr][sc*16]        = pack8(pb0[0], pb0[1]);
        *(half8*)&Bs[sr][sc*16+8]      = pack8(pb0[2], pb0[3]);
        *(half8*)&Bs[sr+128][sc*16]    = pack8(pb1[0], pb1[1]);
        *(half8*)&Bs[sr+128][sc*16+8]  = pack8(pb1[2], pb1[3]);
        __syncthreads();
        if (tile + 1 < 64) stage_load(tile + 1);
        half8 bf[4];
        #pragma unroll
        for (int g = 0; g < 4; ++g) bf[g] = *(const half8*)&Bs[g*64 + w*16 + lr][q*8];
        #pragma unroll
        for (int mt = 0; mt < 8; ++mt) {
            half8 a = *(const half8*)&As[mt*16 + lr][q*8];
            #pragma unroll
            for (int g = 0; g < 4; ++g)
                acc[mt][g] = __builtin_amdgcn_mfma_f32_16x16x32_f16(a, bf[g], acc[mt][g], 0, 0, 0);
        }
    }
    const int h = hblk + w * 16 + lr;
    float bs0 = bih[h] + bhh[h];
    float bs1 = bih[1024+h] + bhh[1024+h];
    float bs2 = bih[2048+h] + bhh[2048+h];
    float bs3 = bih[3072+h] + bhh[3072+h];
    const size_t c_off = (size_t)Btot * 1024;
    #pragma unroll
    for (int mt = 0; mt < 8; ++mt)
        #pragma unroll
        for (int r = 0; r < 4; ++r) {
            const int m = m0 + mt*16 + q*4 + r;
            const size_t idx = (size_t)m * 1024 + h;
            float gi = acc[mt][0][r]+bs0, gf = acc[mt][1][r]+bs1;
            float gc = acc[mt][2][r]+bs2, go = acc[mt][3][r]+bs3;
            float ig = sigmoidf_(gi), fg = sigmoidf_(gf);
            float cd = tanh_fast(gc), og = sigmoidf_(go);
            float c_new = Cprev[idx]*fg + ig*cd;
            Out[idx] = tanh_fast(c_new)*og;
            Out[c_off+idx] = c_new;
        }
}

extern "C" void kernel_launch(void* const* d_in, const int* in_sizes, int n_in,
                              void* d_out, int out_size, void* d_ws, size_t ws_size,
                              hipStream_t stream) {
    const float* X     = (const float*)d_in[0];
    const float* Hprev = (const float*)d_in[1];
    const float* Cprev = (const float*)d_in[2];
    const float* Wih   = (const float*)d_in[3];
    const float* Whh   = (const float*)d_in[4];
    const float* bih   = (const float*)d_in[5];
    const float* bhh   = (const float*)d_in[6];
    float* Out = (float*)d_out;

    const int Btot = in_sizes[0] / 1024;
    const long nX = (long)Btot * 1024, nW = 4096L * 1024;
    const size_t need = (size_t)(2 * nX + 2 * nW) * sizeof(_Float16);

    if (ws_size >= need && (Btot % 256) == 0) {
        _Float16* ws = (_Float16*)d_ws;
        const long total = 2 * nX + 2 * nW;
        const int cblocks = (int)((total / 8 + 255) / 256);
        hipLaunchKernelGGL(convert_to_f16, dim3(cblocks), dim3(256), 0, stream,
                           X, Hprev, Wih, Whh, ws, nX, nW);
        const int mblocks = Btot / 256;               // 64
        const int nblocks = 1024 / 64;                // 16
        hipLaunchKernelGGL(lstm_mfma_v6, dim3(mblocks * nblocks), dim3(512), 0, stream,
                           ws, Cprev, bih, bhh, Out, Btot, mblocks);
    } else {
        const int mblocks = Btot / 128;
        hipLaunchKernelGGL(lstm_mfma_f16_fb, dim3(mblocks * 16), dim3(256), 0, stream,
                           X, Hprev, Cprev, Wih, Whh, bih, bhh, Out, Btot, mblocks);
    }
}